// Round 20
// baseline (163.781 us; speedup 1.0000x reference)
//
#include <hip/hip_runtime.h>

// B=8, N=1024, C=768, H=12, D=64.
// Pipeline: [convert x -> bf16] [transpose+convert Wqkv, Wproj -> Bt bf16]
//           [gemm_qkv: 128Mx64N, 24KB, XCD-pinned A, packed vT stores;
//            q pre-scaled by D^-0.5 * log2(e)]
//           [attn R20: K fragments DIRECT FROM GLOBAL (L2-hot, no LDS);
//            V + per-wave P in LDS; exp2-softmax + truncated P]
//           [gemm_proj R6: 64x128/4w -> f32 out + bias]
// R20: attn LDS-pipe relief. R19 accounting: 405 LDS-cy/wave-iter matches
//      measured 52.7us (saturated). Dropping K from LDS removes 8 reads +
//      1 staging write -> ~300 cy. K is L2-resident (8 same-bh blocks/XCD).

typedef short  bf16x8_t __attribute__((ext_vector_type(8)));
typedef float  f32x4_t  __attribute__((ext_vector_type(4)));

static __device__ __forceinline__ unsigned short f2bf(float f) {
    union { float f; unsigned u; } v; v.f = f;
    unsigned r = v.u + 0x7fffu + ((v.u >> 16) & 1u);   // RNE
    return (unsigned short)(r >> 16);
}

typedef __attribute__((address_space(1))) const unsigned gas_u32;
typedef __attribute__((address_space(3))) unsigned las_u32;
static __device__ __forceinline__ void gload16(const void* g, void* l) {
    __builtin_amdgcn_global_load_lds((gas_u32*)g, (las_u32*)l, 16, 0, 0);
}

#define WAIT0 asm volatile("s_waitcnt vmcnt(0)" ::: "memory")
#define BAR   __builtin_amdgcn_s_barrier()

// Stage a [ROWS x 64] bf16 tile from row-major src (stride 768 u16) into
// linear LDS via gload_lds, chunk-XOR swizzle applied on the GLOBAL source.
#define STAGE_TILE(DST, SRC, K0, NP, NT)                                   \
    _Pragma("unroll")                                                      \
    for (int p_ = 0; p_ < NP; ++p_) {                                      \
        const int base_ = p_*NT + wb;                                      \
        const int i_ = base_ + lane;                                       \
        const int row_ = i_ >> 3;                                          \
        const int cb_ = ((i_ & 7) ^ (row_ & 7)) * 8;                       \
        gload16((SRC) + (size_t)row_*768 + (K0) + cb_, &(DST)[base_*8]);   \
    }

// 2(m) x 4(n) frag compute, wave rows wm*32, cols wn*64 (64x128 tile) — proj.
#define COMPUTE_P(AS, BS)                                                  \
    {                                                                      \
        bf16x8_t a_[2][2], b_[2][4];                                       \
        _Pragma("unroll")                                                  \
        for (int ks_ = 0; ks_ < 2; ++ks_) {                                \
            _Pragma("unroll")                                              \
            for (int m_ = 0; m_ < 2; ++m_) {                               \
                const int ra_ = wm*32 + m_*16 + l15;                       \
                a_[ks_][m_] = *(const bf16x8_t*)&(AS)[ra_*64 + ((ks_*4 + lhi) ^ (ra_ & 7))*8]; \
            }                                                              \
            _Pragma("unroll")                                              \
            for (int n_ = 0; n_ < 4; ++n_) {                               \
                const int rb_ = wn*64 + n_*16 + l15;                       \
                b_[ks_][n_] = *(const bf16x8_t*)&(BS)[rb_*64 + ((ks_*4 + lhi) ^ (rb_ & 7))*8]; \
            }                                                              \
        }                                                                  \
        _Pragma("unroll")                                                  \
        for (int m_ = 0; m_ < 2; ++m_)                                     \
            _Pragma("unroll")                                              \
            for (int n_ = 0; n_ < 4; ++n_) {                               \
                acc[m_][n_] = __builtin_amdgcn_mfma_f32_16x16x32_bf16(a_[0][m_], b_[0][n_], acc[m_][n_], 0, 0, 0); \
                acc[m_][n_] = __builtin_amdgcn_mfma_f32_16x16x32_bf16(a_[1][m_], b_[1][n_], acc[m_][n_], 0, 0, 0); \
            }                                                              \
    }

// 4(m) x 2(n) frag compute, wave rows wm*64, cols wn*32 (128x64 tile) — qkv.
#define COMPUTE_Q2(AS, BS)                                                 \
    {                                                                      \
        bf16x8_t a_[2][4], b_[2][2];                                       \
        _Pragma("unroll")                                                  \
        for (int ks_ = 0; ks_ < 2; ++ks_) {                                \
            _Pragma("unroll")                                              \
            for (int m_ = 0; m_ < 4; ++m_) {                               \
                const int ra_ = wm*64 + m_*16 + l15;                       \
                a_[ks_][m_] = *(const bf16x8_t*)&(AS)[ra_*64 + ((ks_*4 + lhi) ^ (ra_ & 7))*8]; \
            }                                                              \
            _Pragma("unroll")                                              \
            for (int n_ = 0; n_ < 2; ++n_) {                               \
                const int rb_ = wn*32 + n_*16 + l15;                       \
                b_[ks_][n_] = *(const bf16x8_t*)&(BS)[rb_*64 + ((ks_*4 + lhi) ^ (rb_ & 7))*8]; \
            }                                                              \
        }                                                                  \
        _Pragma("unroll")                                                  \
        for (int m_ = 0; m_ < 4; ++m_)                                     \
            _Pragma("unroll")                                              \
            for (int n_ = 0; n_ < 2; ++n_) {                               \
                acc[m_][n_] = __builtin_amdgcn_mfma_f32_16x16x32_bf16(a_[0][m_], b_[0][n_], acc[m_][n_], 0, 0, 0); \
                acc[m_][n_] = __builtin_amdgcn_mfma_f32_16x16x32_bf16(a_[1][m_], b_[1][n_], acc[m_][n_], 0, 0, 0); \
            }                                                              \
    }

// ---------------- pre-pass: x f32 -> bf16 (same layout)
__global__ __launch_bounds__(256) void convert_x(
    const float* __restrict__ src, unsigned short* __restrict__ dst)
{
    const int i = blockIdx.x * 256 + threadIdx.x;
    const float4 v = ((const float4*)src)[i];
    ushort4 o; o.x = f2bf(v.x); o.y = f2bf(v.y); o.z = f2bf(v.z); o.w = f2bf(v.w);
    ((ushort4*)dst)[i] = o;
}

// ---------------- pre-pass: W [R][C] f32 -> Wt [C][R] bf16
__global__ __launch_bounds__(256) void transpose_cvt(
    const float* __restrict__ src, unsigned short* __restrict__ dst, int R, int C)
{
    __shared__ unsigned short tile[32][33];
    const int tx = threadIdx.x & 31, ty = threadIdx.x >> 5;
    const int bx = blockIdx.x, by = blockIdx.y;
    #pragma unroll
    for (int j = 0; j < 32; j += 8)
        tile[ty + j][tx] = f2bf(src[(size_t)(by*32 + ty + j) * C + bx*32 + tx]);
    __syncthreads();
    #pragma unroll
    for (int j = 0; j < 32; j += 8)
        dst[(size_t)(bx*32 + ty + j) * R + by*32 + tx] = tile[tx][ty + j];
}

// ---------------- GEMM1: 128x64 tile, 4 waves, 24KB, packed vT stores
__global__ __launch_bounds__(256, 6) void gemm_qkv_bf16(
    const unsigned short* __restrict__ A, const unsigned short* __restrict__ Bt,
    const float* __restrict__ bias,
    unsigned short* __restrict__ q, unsigned short* __restrict__ kO,
    unsigned short* __restrict__ vT)
{
    __shared__ unsigned short As[128*64];   // 16KB
    __shared__ unsigned short Bs[64*64];    // 8KB
    const int tid = threadIdx.x;
    const int id = blockIdx.x;              // 2304 blocks, 2304%8==0
    const int xcd = id & 7, r = id >> 3;    // r 0..287
    const int nb = r >> 3;                  // 0..35 (one 96KB panel per 8 blocks)
    const int mb = (r & 7) * 8 + xcd;       // 0..63 (8 per XCD, pinned)
    const int n0 = nb * 64, m0 = mb * 128;

    const int lane = tid & 63, w = tid >> 6;
    const int l15 = lane & 15, lhi = lane >> 4;
    const int wm = w >> 1, wn = w & 1;      // 2x2 wave grid
    const int wb = tid & 192;

    const unsigned short* Ab = A  + (size_t)m0 * 768;
    const unsigned short* Bb = Bt + (size_t)n0 * 768;

    f32x4_t acc[4][2] = {};

    #pragma unroll 1
    for (int t = 0; t < 12; ++t) {
        STAGE_TILE(As, Ab, t*64, 4, 256)
        STAGE_TILE(Bs, Bb, t*64, 2, 256)
        WAIT0; BAR;
        COMPUTE_Q2(As, Bs)
        BAR;
    }

    // epilogue: qkv scatter. kk block-uniform (64 | 768).
    // q pre-scaled by D^-0.5 * log2(e) so attn can use exp2 directly.
    #pragma unroll
    for (int n = 0; n < 2; ++n) {
        const int gcol = n0 + wn*32 + n*16 + l15;         // 0..2303
        const int kk = gcol / 768;                        // 0=q,1=k,2=v
        const int rr = gcol - kk*768;
        const int h  = rr >> 6, d = rr & 63;
        const float bv = bias[gcol];
        const float sc = (kk == 0) ? 0.18033688f : 1.0f;  // 0.125 * log2(e)
        #pragma unroll
        for (int m = 0; m < 4; ++m) {
            const int grow_base = m0 + wm*64 + m*16 + lhi*4;  // 4-aligned, one b
            const int bb = grow_base >> 10, seq0 = grow_base & 1023;
            const size_t bh = (size_t)bb*12 + h;
            ushort4 o4;
            o4.x = f2bf((acc[m][n][0] + bv) * sc);
            o4.y = f2bf((acc[m][n][1] + bv) * sc);
            o4.z = f2bf((acc[m][n][2] + bv) * sc);
            o4.w = f2bf((acc[m][n][3] + bv) * sc);
            if (kk == 2) {                    // v: 4 consecutive seq -> one 8B store
                *(ushort4*)(vT + (bh*64 + d)*1024 + seq0) = o4;
            } else {
                unsigned short* dst = (kk == 0) ? q : kO;
                dst[(bh*1024 + seq0 + 0)*64 + d] = o4.x;
                dst[(bh*1024 + seq0 + 1)*64 + d] = o4.y;
                dst[(bh*1024 + seq0 + 2)*64 + d] = o4.z;
                dst[(bh*1024 + seq0 + 3)*64 + d] = o4.w;
            }
        }
    }
}

// ---------------- Attention (R20): K direct from global; V + P in LDS
__global__ __launch_bounds__(512, 6) void attn2(
    const unsigned short* __restrict__ q, const unsigned short* __restrict__ k,
    const unsigned short* __restrict__ vT, unsigned short* __restrict__ obuf)
{
    __shared__ unsigned short Vs[64 * 72];     // 9216 B
    __shared__ unsigned short P[8][16 * 72];   // 18432 B -> total 27648 B
    const int tid = threadIdx.x;
    const int id = blockIdx.x;                 // 768 blocks, 768%8==0
    const int swz = (id & 7) * 96 + (id >> 3);
    const int qt = swz & 7, bh = swz >> 3;     // 8 same-bh blocks per XCD run

    const int lane = tid & 63, w = tid >> 6;   // w 0..7
    const int l15 = lane & 15, lhi = lane >> 4;
    const unsigned short* qp = q  + (size_t)bh * 65536;
    const unsigned short* kp = k  + (size_t)bh * 65536;
    const unsigned short* vp = vT + (size_t)bh * 65536;  // [64 d][1024 n]

    bf16x8_t qf[2];
    const int qrow = qt*128 + w*16 + l15;
    #pragma unroll
    for (int ks = 0; ks < 2; ++ks)
        qf[ks] = *(const bf16x8_t*)(qp + (size_t)qrow*64 + ks*32 + lhi*8);

    f32x4_t acco[4] = {};
    float lsum[4] = {0.f, 0.f, 0.f, 0.f};
    unsigned short* Pw = P[w];

    const int r8 = tid >> 3, cb = (tid & 7) * 8;
    bf16x8_t vr;
    vr = *(const bf16x8_t*)(vp + (size_t)r8*1024 + cb);
    *(bf16x8_t*)&Vs[r8*72 + cb] = vr;

    for (int kt = 0; kt < 16; ++kt) {
        __syncthreads();                       // Vs staged & visible
        if (kt < 15)                           // T14: issue next V tile now
            vr = *(const bf16x8_t*)(vp + (size_t)r8*1024 + (kt+1)*64 + cb);

        // QK^T: K fragments straight from global (L2-hot)
        f32x4_t accs[4] = {};
        __builtin_amdgcn_s_setprio(1);
        #pragma unroll
        for (int c = 0; c < 4; ++c)
            #pragma unroll
            for (int ks = 0; ks < 2; ++ks) {
                bf16x8_t kf = *(const bf16x8_t*)(kp + (size_t)(kt*64 + c*16 + l15)*64 + ks*32 + lhi*8);
                accs[c] = __builtin_amdgcn_mfma_f32_16x16x32_bf16(qf[ks], kf, accs[c], 0, 0, 0);
            }
        __builtin_amdgcn_s_setprio(0);

        // softmax numerator: S pre-scaled by log2(e) -> exp2; truncated bf16.
        #pragma unroll
        for (int c = 0; c < 4; ++c)
            #pragma unroll
            for (int r = 0; r < 4; ++r) {
                const float pv = __builtin_amdgcn_exp2f(accs[c][r]);
                lsum[r] += pv;
                union { float f; unsigned u; } uu; uu.f = pv;
                Pw[(lhi*4 + r)*72 + c*16 + l15] = (unsigned short)(uu.u >> 16);
            }

        bf16x8_t pf[2];
        #pragma unroll
        for (int ks = 0; ks < 2; ++ks)
            pf[ks] = *(const bf16x8_t*)&Pw[l15*72 + ks*32 + lhi*8];
        __builtin_amdgcn_s_setprio(1);
        #pragma unroll
        for (int n = 0; n < 4; ++n)
            #pragma unroll
            for (int ks = 0; ks < 2; ++ks) {
                bf16x8_t vf = *(const bf16x8_t*)&Vs[(n*16 + l15)*72 + ks*32 + lhi*8];
                acco[n] = __builtin_amdgcn_mfma_f32_16x16x32_bf16(pf[ks], vf, acco[n], 0, 0, 0);
            }
        __builtin_amdgcn_s_setprio(0);

        __syncthreads();                       // all waves done reading Vs
        if (kt < 15)                           // write-late into single buffer
            *(bf16x8_t*)&Vs[r8*72 + cb] = vr;
    }

    #pragma unroll
    for (int r = 0; r < 4; ++r)
        #pragma unroll
        for (int off = 1; off <= 8; off <<= 1)
            lsum[r] += __shfl_xor(lsum[r], off, 64);

    const int b = bh / 12, h = bh % 12;
    #pragma unroll
    for (int n = 0; n < 4; ++n)
        #pragma unroll
        for (int r = 0; r < 4; ++r) {
            const int seq = qt*128 + w*16 + lhi*4 + r;
            obuf[((size_t)(b*1024 + seq))*768 + h*64 + n*16 + l15] = f2bf(acco[n][r] / lsum[r]);
        }
}

// ---------------- GEMM2 (R6 + 6/CU): 64x128 tile, 4 waves, 24KB buffer
__global__ __launch_bounds__(256, 6) void gemm_proj_bf16(
    const unsigned short* __restrict__ A, const unsigned short* __restrict__ Bt,
    const float* __restrict__ bias, float* __restrict__ out)
{
    __shared__ unsigned short As[64*64];
    __shared__ unsigned short Bs[128*64];
    const int tid = threadIdx.x;
    const int id = blockIdx.x;              // 768 blocks
    const int swz = (id & 7) * 96 + (id >> 3);
    const int n0 = (swz % 6) * 128, m0 = (swz / 6) * 64;

    const int lane = tid & 63, w = tid >> 6;
    const int l15 = lane & 15, lhi = lane >> 4;
    const int wm = w >> 1, wn = w & 1;
    const int wb = tid & 192;

    const unsigned short* Ab = A  + (size_t)m0 * 768;
    const unsigned short* Bb = Bt + (size_t)n0 * 768;

    f32x4_t acc[2][4] = {};

    #pragma unroll 1
    for (int t = 0; t < 12; ++t) {
        STAGE_TILE(As, Ab, t*64, 2, 256)
        STAGE_TILE(Bs, Bb, t*64, 4, 256)
        WAIT0; BAR;
        COMPUTE_P(As, Bs)
        BAR;
    }

    #pragma unroll
    for (int n = 0; n < 4; ++n) {
        const int gcol = n0 + wn*64 + n*16 + l15;
        const float bv = bias[gcol];
        #pragma unroll
        for (int m = 0; m < 2; ++m) {
            const int grow_base = m0 + wm*32 + m*16 + lhi*4;
            #pragma unroll
            for (int reg = 0; reg < 4; ++reg)
                out[(size_t)(grow_base + reg)*768 + gcol] = acc[m][n][reg] + bv;
        }
    }
}

extern "C" void kernel_launch(void* const* d_in, const int* in_sizes, int n_in,
                              void* d_out, int out_size, void* d_ws, size_t ws_size,
                              hipStream_t stream) {
    const float* x     = (const float*)d_in[0];
    const float* Wqkv  = (const float*)d_in[1];
    const float* bqkv  = (const float*)d_in[2];
    const float* Wproj = (const float*)d_in[3];
    const float* bproj = (const float*)d_in[4];
    float* out = (float*)d_out;
    unsigned short* ws = (unsigned short*)d_ws;

    unsigned short* xb    = ws;                       // 6291456
    unsigned short* obuf  = ws;                       // alias (xb dead after gemm_qkv)
    unsigned short* wqt   = ws + 6291456u;            // 1769472
    unsigned short* wpt   = ws + 8060928u;            // 589824
    unsigned short* qb    = ws + 8650752u;            // 6291456
    unsigned short* kb    = ws + 14942208u;           // 6291456
    unsigned short* vTb   = ws + 21233664u;           // 6291456

    convert_x     <<<6144, 256, 0, stream>>>(x, xb);
    transpose_cvt <<<dim3(72, 24), 256, 0, stream>>>(Wqkv, wqt, 768, 2304);
    transpose_cvt <<<dim3(24, 24), 256, 0, stream>>>(Wproj, wpt, 768, 768);
    gemm_qkv_bf16 <<<2304, 256, 0, stream>>>(xb, wqt, bqkv, qb, kb, vTb);
    attn2         <<<768,  512, 0, stream>>>(qb, kb, vTb, obuf);
    gemm_proj_bf16<<<768,  256, 0, stream>>>(obuf, wpt, bproj, out);
}

// Round 21
// 119.681 us; speedup vs baseline: 1.3685x; 1.3685x over previous
//
#include <hip/hip_runtime.h>

// B=8, N=1024, C=768, H=12, D=64.
// Pipeline: [convert x -> bf16] [transpose+convert Wqkv, Wproj -> Bt bf16]
//           [gemm_qkv R21: 256Mx64N tile, 40KB, 4/CU, 1152 blocks (1.125
//            rounds), 0.56 LDS-reads/MFMA; packed vT; q pre-scaled]
//           [attn R19 (reverted from R20): K+V+P in LDS, reg prefetch,
//            exp2-softmax + truncated P, stride 72]
//           [gemm_proj R6: 64x128/4w -> f32 out + bias]
// R21: R20's global-K refuted (103us — strided frag loads latency-bound;
//      frag reads MUST be LDS). qkv: bigger M-tile fixes 1.5-round tail
//      and cuts reads/MFMA 0.75->0.56.

typedef short  bf16x8_t __attribute__((ext_vector_type(8)));
typedef float  f32x4_t  __attribute__((ext_vector_type(4)));

static __device__ __forceinline__ unsigned short f2bf(float f) {
    union { float f; unsigned u; } v; v.f = f;
    unsigned r = v.u + 0x7fffu + ((v.u >> 16) & 1u);   // RNE
    return (unsigned short)(r >> 16);
}

typedef __attribute__((address_space(1))) const unsigned gas_u32;
typedef __attribute__((address_space(3))) unsigned las_u32;
static __device__ __forceinline__ void gload16(const void* g, void* l) {
    __builtin_amdgcn_global_load_lds((gas_u32*)g, (las_u32*)l, 16, 0, 0);
}

#define WAIT0 asm volatile("s_waitcnt vmcnt(0)" ::: "memory")
#define BAR   __builtin_amdgcn_s_barrier()

// Stage a [ROWS x 64] bf16 tile from row-major src (stride 768 u16) into
// linear LDS via gload_lds, chunk-XOR swizzle applied on the GLOBAL source.
#define STAGE_TILE(DST, SRC, K0, NP, NT)                                   \
    _Pragma("unroll")                                                      \
    for (int p_ = 0; p_ < NP; ++p_) {                                      \
        const int base_ = p_*NT + wb;                                      \
        const int i_ = base_ + lane;                                       \
        const int row_ = i_ >> 3;                                          \
        const int cb_ = ((i_ & 7) ^ (row_ & 7)) * 8;                       \
        gload16((SRC) + (size_t)row_*768 + (K0) + cb_, &(DST)[base_*8]);   \
    }

// 2(m) x 4(n) frag compute, wave rows wm*32, cols wn*64 (64x128 tile) — proj.
#define COMPUTE_P(AS, BS)                                                  \
    {                                                                      \
        bf16x8_t a_[2][2], b_[2][4];                                       \
        _Pragma("unroll")                                                  \
        for (int ks_ = 0; ks_ < 2; ++ks_) {                                \
            _Pragma("unroll")                                              \
            for (int m_ = 0; m_ < 2; ++m_) {                               \
                const int ra_ = wm*32 + m_*16 + l15;                       \
                a_[ks_][m_] = *(const bf16x8_t*)&(AS)[ra_*64 + ((ks_*4 + lhi) ^ (ra_ & 7))*8]; \
            }                                                              \
            _Pragma("unroll")                                              \
            for (int n_ = 0; n_ < 4; ++n_) {                               \
                const int rb_ = wn*64 + n_*16 + l15;                       \
                b_[ks_][n_] = *(const bf16x8_t*)&(BS)[rb_*64 + ((ks_*4 + lhi) ^ (rb_ & 7))*8]; \
            }                                                              \
        }                                                                  \
        _Pragma("unroll")                                                  \
        for (int m_ = 0; m_ < 2; ++m_)                                     \
            _Pragma("unroll")                                              \
            for (int n_ = 0; n_ < 4; ++n_) {                               \
                acc[m_][n_] = __builtin_amdgcn_mfma_f32_16x16x32_bf16(a_[0][m_], b_[0][n_], acc[m_][n_], 0, 0, 0); \
                acc[m_][n_] = __builtin_amdgcn_mfma_f32_16x16x32_bf16(a_[1][m_], b_[1][n_], acc[m_][n_], 0, 0, 0); \
            }                                                              \
    }

// 8(m) x 2(n) frag compute, wave rows wm*128, cols wn*32 (256x64 tile) — qkv.
// ks-outer caps live frag regs: a[8]+b[2]=40 + acc 64 ~ fits 128-VGPR budget.
#define COMPUTE_Q3(AS, BS)                                                 \
    _Pragma("unroll")                                                      \
    for (int ks_ = 0; ks_ < 2; ++ks_) {                                    \
        bf16x8_t a_[8], b_[2];                                             \
        _Pragma("unroll")                                                  \
        for (int m_ = 0; m_ < 8; ++m_) {                                   \
            const int ra_ = wm*128 + m_*16 + l15;                          \
            a_[m_] = *(const bf16x8_t*)&(AS)[ra_*64 + ((ks_*4 + lhi) ^ (ra_ & 7))*8]; \
        }                                                                  \
        _Pragma("unroll")                                                  \
        for (int n_ = 0; n_ < 2; ++n_) {                                   \
            const int rb_ = wn*32 + n_*16 + l15;                           \
            b_[n_] = *(const bf16x8_t*)&(BS)[rb_*64 + ((ks_*4 + lhi) ^ (rb_ & 7))*8]; \
        }                                                                  \
        _Pragma("unroll")                                                  \
        for (int m_ = 0; m_ < 8; ++m_)                                     \
            _Pragma("unroll")                                              \
            for (int n_ = 0; n_ < 2; ++n_)                                 \
                acc[m_][n_] = __builtin_amdgcn_mfma_f32_16x16x32_bf16(a_[m_], b_[n_], acc[m_][n_], 0, 0, 0); \
    }

// ---------------- pre-pass: x f32 -> bf16 (same layout)
__global__ __launch_bounds__(256) void convert_x(
    const float* __restrict__ src, unsigned short* __restrict__ dst)
{
    const int i = blockIdx.x * 256 + threadIdx.x;
    const float4 v = ((const float4*)src)[i];
    ushort4 o; o.x = f2bf(v.x); o.y = f2bf(v.y); o.z = f2bf(v.z); o.w = f2bf(v.w);
    ((ushort4*)dst)[i] = o;
}

// ---------------- pre-pass: W [R][C] f32 -> Wt [C][R] bf16
__global__ __launch_bounds__(256) void transpose_cvt(
    const float* __restrict__ src, unsigned short* __restrict__ dst, int R, int C)
{
    __shared__ unsigned short tile[32][33];
    const int tx = threadIdx.x & 31, ty = threadIdx.x >> 5;
    const int bx = blockIdx.x, by = blockIdx.y;
    #pragma unroll
    for (int j = 0; j < 32; j += 8)
        tile[ty + j][tx] = f2bf(src[(size_t)(by*32 + ty + j) * C + bx*32 + tx]);
    __syncthreads();
    #pragma unroll
    for (int j = 0; j < 32; j += 8)
        dst[(size_t)(bx*32 + ty + j) * R + by*32 + tx] = tile[tx][ty + j];
}

// ---------------- GEMM1 (R21): 256x64 tile, 4 waves, 40KB, 4/CU
__global__ __launch_bounds__(256, 4) void gemm_qkv_bf16(
    const unsigned short* __restrict__ A, const unsigned short* __restrict__ Bt,
    const float* __restrict__ bias,
    unsigned short* __restrict__ q, unsigned short* __restrict__ kO,
    unsigned short* __restrict__ vT)
{
    __shared__ unsigned short As[256*64];   // 32KB
    __shared__ unsigned short Bs[64*64];    // 8KB
    const int tid = threadIdx.x;
    const int id = blockIdx.x;              // 1152 blocks, 1152%8==0
    const int xcd = id & 7, r = id >> 3;    // r 0..143
    const int nb = r >> 2;                  // 0..35 (one 96KB panel per 4 blocks)
    const int mb = (r & 3) * 8 + xcd;       // 0..31 (4 per XCD, pinned 1.5MB)
    const int n0 = nb * 64, m0 = mb * 256;

    const int lane = tid & 63, w = tid >> 6;
    const int l15 = lane & 15, lhi = lane >> 4;
    const int wm = w >> 1, wn = w & 1;      // 2x2 wave grid, wave = 128x32
    const int wb = tid & 192;

    const unsigned short* Ab = A  + (size_t)m0 * 768;
    const unsigned short* Bb = Bt + (size_t)n0 * 768;

    f32x4_t acc[8][2] = {};

    #pragma unroll 1
    for (int t = 0; t < 12; ++t) {
        STAGE_TILE(As, Ab, t*64, 8, 256)
        STAGE_TILE(Bs, Bb, t*64, 2, 256)
        WAIT0; BAR;
        COMPUTE_Q3(As, Bs)
        BAR;
    }

    // epilogue: qkv scatter. kk block-uniform (64 | 768).
    // q pre-scaled by D^-0.5 * log2(e) so attn can use exp2 directly.
    #pragma unroll
    for (int n = 0; n < 2; ++n) {
        const int gcol = n0 + wn*32 + n*16 + l15;         // 0..2303
        const int kk = gcol / 768;                        // 0=q,1=k,2=v
        const int rr = gcol - kk*768;
        const int h  = rr >> 6, d = rr & 63;
        const float bv = bias[gcol];
        const float sc = (kk == 0) ? 0.18033688f : 1.0f;  // 0.125 * log2(e)
        #pragma unroll
        for (int m = 0; m < 8; ++m) {
            const int grow_base = m0 + wm*128 + m*16 + lhi*4;  // 4-aligned, one b
            const int bb = grow_base >> 10, seq0 = grow_base & 1023;
            const size_t bh = (size_t)bb*12 + h;
            ushort4 o4;
            o4.x = f2bf((acc[m][n][0] + bv) * sc);
            o4.y = f2bf((acc[m][n][1] + bv) * sc);
            o4.z = f2bf((acc[m][n][2] + bv) * sc);
            o4.w = f2bf((acc[m][n][3] + bv) * sc);
            if (kk == 2) {                    // v: 4 consecutive seq -> one 8B store
                *(ushort4*)(vT + (bh*64 + d)*1024 + seq0) = o4;
            } else {
                unsigned short* dst = (kk == 0) ? q : kO;
                dst[(bh*1024 + seq0 + 0)*64 + d] = o4.x;
                dst[(bh*1024 + seq0 + 1)*64 + d] = o4.y;
                dst[(bh*1024 + seq0 + 2)*64 + d] = o4.z;
                dst[(bh*1024 + seq0 + 3)*64 + d] = o4.w;
            }
        }
    }
}

// ---------------- Attention (R19, verified best): K+V+P in LDS, exp2, trunc
__global__ __launch_bounds__(512, 6) void attn2(
    const unsigned short* __restrict__ q, const unsigned short* __restrict__ k,
    const unsigned short* __restrict__ vT, unsigned short* __restrict__ obuf)
{
    __shared__ unsigned short Ks[64 * 72];
    __shared__ unsigned short Vs[64 * 72];
    __shared__ unsigned short P[8][16 * 72];   // stride 72: b128 reads 16B-aligned
    const int tid = threadIdx.x;
    const int id = blockIdx.x;                 // 768 blocks, 768%8==0
    const int swz = (id & 7) * 96 + (id >> 3);
    const int qt = swz & 7, bh = swz >> 3;     // 8 q-tiles of 128, 96 bh

    const int lane = tid & 63, w = tid >> 6;   // w 0..7
    const int l15 = lane & 15, lhi = lane >> 4;
    const unsigned short* qp = q  + (size_t)bh * 65536;
    const unsigned short* kp = k  + (size_t)bh * 65536;
    const unsigned short* vp = vT + (size_t)bh * 65536;  // [64 d][1024 n]

    bf16x8_t qf[2];
    const int qrow = qt*128 + w*16 + l15;
    #pragma unroll
    for (int ks = 0; ks < 2; ++ks)
        qf[ks] = *(const bf16x8_t*)(qp + (size_t)qrow*64 + ks*32 + lhi*8);

    f32x4_t acco[4] = {};
    float lsum[4] = {0.f, 0.f, 0.f, 0.f};
    unsigned short* Pw = P[w];

    const int r8 = tid >> 3, cb = (tid & 7) * 8;
    bf16x8_t kr, vr;
    kr = *(const bf16x8_t*)(kp + (size_t)r8*64 + cb);
    vr = *(const bf16x8_t*)(vp + (size_t)r8*1024 + cb);
    *(bf16x8_t*)&Ks[r8*72 + cb] = kr;
    *(bf16x8_t*)&Vs[r8*72 + cb] = vr;

    for (int kt = 0; kt < 16; ++kt) {
        __syncthreads();
        if (kt < 15) {                         // T14: issue next-tile loads now
            kr = *(const bf16x8_t*)(kp + (size_t)((kt+1)*64 + r8)*64 + cb);
            vr = *(const bf16x8_t*)(vp + (size_t)r8*1024 + (kt+1)*64 + cb);
        }

        f32x4_t accs[4] = {};
        __builtin_amdgcn_s_setprio(1);
        #pragma unroll
        for (int c = 0; c < 4; ++c)
            #pragma unroll
            for (int ks = 0; ks < 2; ++ks) {
                bf16x8_t kf = *(const bf16x8_t*)&Ks[(c*16 + l15)*72 + ks*32 + lhi*8];
                accs[c] = __builtin_amdgcn_mfma_f32_16x16x32_bf16(qf[ks], kf, accs[c], 0, 0, 0);
            }
        __builtin_amdgcn_s_setprio(0);

        // softmax numerator: S pre-scaled by log2(e) -> exp2; truncated bf16.
        #pragma unroll
        for (int c = 0; c < 4; ++c)
            #pragma unroll
            for (int r = 0; r < 4; ++r) {
                const float pv = __builtin_amdgcn_exp2f(accs[c][r]);
                lsum[r] += pv;
                union { float f; unsigned u; } uu; uu.f = pv;
                Pw[(lhi*4 + r)*72 + c*16 + l15] = (unsigned short)(uu.u >> 16);
            }

        bf16x8_t pf[2];
        #pragma unroll
        for (int ks = 0; ks < 2; ++ks)
            pf[ks] = *(const bf16x8_t*)&Pw[l15*72 + ks*32 + lhi*8];
        __builtin_amdgcn_s_setprio(1);
        #pragma unroll
        for (int n = 0; n < 4; ++n)
            #pragma unroll
            for (int ks = 0; ks < 2; ++ks) {
                bf16x8_t vf = *(const bf16x8_t*)&Vs[(n*16 + l15)*72 + ks*32 + lhi*8];
                acco[n] = __builtin_amdgcn_mfma_f32_16x16x32_bf16(pf[ks], vf, acco[n], 0, 0, 0);
            }
        __builtin_amdgcn_s_setprio(0);

        __syncthreads();
        if (kt < 15) {                         // write-late into single buffer
            *(bf16x8_t*)&Ks[r8*72 + cb] = kr;
            *(bf16x8_t*)&Vs[r8*72 + cb] = vr;
        }
    }

    #pragma unroll
    for (int r = 0; r < 4; ++r)
        #pragma unroll
        for (int off = 1; off <= 8; off <<= 1)
            lsum[r] += __shfl_xor(lsum[r], off, 64);

    const int b = bh / 12, h = bh % 12;
    #pragma unroll
    for (int n = 0; n < 4; ++n)
        #pragma unroll
        for (int r = 0; r < 4; ++r) {
            const int seq = qt*128 + w*16 + lhi*4 + r;
            obuf[((size_t)(b*1024 + seq))*768 + h*64 + n*16 + l15] = f2bf(acco[n][r] / lsum[r]);
        }
}

// ---------------- GEMM2 (R6 + 6/CU): 64x128 tile, 4 waves, 24KB buffer
__global__ __launch_bounds__(256, 6) void gemm_proj_bf16(
    const unsigned short* __restrict__ A, const unsigned short* __restrict__ Bt,
    const float* __restrict__ bias, float* __restrict__ out)
{
    __shared__ unsigned short As[64*64];
    __shared__ unsigned short Bs[128*64];
    const int tid = threadIdx.x;
    const int id = blockIdx.x;              // 768 blocks
    const int swz = (id & 7) * 96 + (id >> 3);
    const int n0 = (swz % 6) * 128, m0 = (swz / 6) * 64;

    const int lane = tid & 63, w = tid >> 6;
    const int l15 = lane & 15, lhi = lane >> 4;
    const int wm = w >> 1, wn = w & 1;
    const int wb = tid & 192;

    const unsigned short* Ab = A  + (size_t)m0 * 768;
    const unsigned short* Bb = Bt + (size_t)n0 * 768;

    f32x4_t acc[2][4] = {};

    #pragma unroll 1
    for (int t = 0; t < 12; ++t) {
        STAGE_TILE(As, Ab, t*64, 2, 256)
        STAGE_TILE(Bs, Bb, t*64, 4, 256)
        WAIT0; BAR;
        COMPUTE_P(As, Bs)
        BAR;
    }

    #pragma unroll
    for (int n = 0; n < 4; ++n) {
        const int gcol = n0 + wn*64 + n*16 + l15;
        const float bv = bias[gcol];
        #pragma unroll
        for (int m = 0; m < 2; ++m) {
            const int grow_base = m0 + wm*32 + m*16 + lhi*4;
            #pragma unroll
            for (int reg = 0; reg < 4; ++reg)
                out[(size_t)(grow_base + reg)*768 + gcol] = acc[m][n][reg] + bv;
        }
    }
}

extern "C" void kernel_launch(void* const* d_in, const int* in_sizes, int n_in,
                              void* d_out, int out_size, void* d_ws, size_t ws_size,
                              hipStream_t stream) {
    const float* x     = (const float*)d_in[0];
    const float* Wqkv  = (const float*)d_in[1];
    const float* bqkv  = (const float*)d_in[2];
    const float* Wproj = (const float*)d_in[3];
    const float* bproj = (const float*)d_in[4];
    float* out = (float*)d_out;
    unsigned short* ws = (unsigned short*)d_ws;

    unsigned short* xb    = ws;                       // 6291456
    unsigned short* obuf  = ws;                       // alias (xb dead after gemm_qkv)
    unsigned short* wqt   = ws + 6291456u;            // 1769472
    unsigned short* wpt   = ws + 8060928u;            // 589824
    unsigned short* qb    = ws + 8650752u;            // 6291456
    unsigned short* kb    = ws + 14942208u;           // 6291456
    unsigned short* vTb   = ws + 21233664u;           // 6291456

    convert_x     <<<6144, 256, 0, stream>>>(x, xb);
    transpose_cvt <<<dim3(72, 24), 256, 0, stream>>>(Wqkv, wqt, 768, 2304);
    transpose_cvt <<<dim3(24, 24), 256, 0, stream>>>(Wproj, wpt, 768, 768);
    gemm_qkv_bf16 <<<1152, 256, 0, stream>>>(xb, wqt, bqkv, qb, kb, vTb);
    attn2         <<<768,  512, 0, stream>>>(qb, kb, vTb, obuf);
    gemm_proj_bf16<<<768,  256, 0, stream>>>(obuf, wpt, bproj, out);
}

// Round 22
// 115.293 us; speedup vs baseline: 1.4206x; 1.0381x over previous
//
#include <hip/hip_runtime.h>

// B=8, N=1024, C=768, H=12, D=64.
// Pipeline: [convert x -> bf16] [transpose+convert Wqkv, Wproj -> Bt bf16]
//           [gemm_qkv: 128Mx64N, 24KB, XCD-pinned A, packed vT stores;
//            q pre-scaled by D^-0.5 * log2(e)]
//           [attn: K+V+P in LDS, reg prefetch, exp2-softmax + truncated P,
//            stride 72 (16B-aligned)]
//           [gemm_proj: 64x128/4w -> f32 out + bias]
// R22: exact revert to R19 (best measured 115.6us). R21's 256x64 qkv
//      regressed (40KB/4-per-CU: longer barrier period, thinner TLP).
//      128x64 @ 24KB/6-per-CU is the verified sweet spot at K=768.

typedef short  bf16x8_t __attribute__((ext_vector_type(8)));
typedef float  f32x4_t  __attribute__((ext_vector_type(4)));

static __device__ __forceinline__ unsigned short f2bf(float f) {
    union { float f; unsigned u; } v; v.f = f;
    unsigned r = v.u + 0x7fffu + ((v.u >> 16) & 1u);   // RNE
    return (unsigned short)(r >> 16);
}

typedef __attribute__((address_space(1))) const unsigned gas_u32;
typedef __attribute__((address_space(3))) unsigned las_u32;
static __device__ __forceinline__ void gload16(const void* g, void* l) {
    __builtin_amdgcn_global_load_lds((gas_u32*)g, (las_u32*)l, 16, 0, 0);
}

#define WAIT0 asm volatile("s_waitcnt vmcnt(0)" ::: "memory")
#define BAR   __builtin_amdgcn_s_barrier()

// Stage a [ROWS x 64] bf16 tile from row-major src (stride 768 u16) into
// linear LDS via gload_lds, chunk-XOR swizzle applied on the GLOBAL source.
#define STAGE_TILE(DST, SRC, K0, NP, NT)                                   \
    _Pragma("unroll")                                                      \
    for (int p_ = 0; p_ < NP; ++p_) {                                      \
        const int base_ = p_*NT + wb;                                      \
        const int i_ = base_ + lane;                                       \
        const int row_ = i_ >> 3;                                          \
        const int cb_ = ((i_ & 7) ^ (row_ & 7)) * 8;                       \
        gload16((SRC) + (size_t)row_*768 + (K0) + cb_, &(DST)[base_*8]);   \
    }

// 2(m) x 4(n) frag compute, wave rows wm*32, cols wn*64 (64x128 tile) — proj.
#define COMPUTE_P(AS, BS)                                                  \
    {                                                                      \
        bf16x8_t a_[2][2], b_[2][4];                                       \
        _Pragma("unroll")                                                  \
        for (int ks_ = 0; ks_ < 2; ++ks_) {                                \
            _Pragma("unroll")                                              \
            for (int m_ = 0; m_ < 2; ++m_) {                               \
                const int ra_ = wm*32 + m_*16 + l15;                       \
                a_[ks_][m_] = *(const bf16x8_t*)&(AS)[ra_*64 + ((ks_*4 + lhi) ^ (ra_ & 7))*8]; \
            }                                                              \
            _Pragma("unroll")                                              \
            for (int n_ = 0; n_ < 4; ++n_) {                               \
                const int rb_ = wn*64 + n_*16 + l15;                       \
                b_[ks_][n_] = *(const bf16x8_t*)&(BS)[rb_*64 + ((ks_*4 + lhi) ^ (rb_ & 7))*8]; \
            }                                                              \
        }                                                                  \
        _Pragma("unroll")                                                  \
        for (int m_ = 0; m_ < 2; ++m_)                                     \
            _Pragma("unroll")                                              \
            for (int n_ = 0; n_ < 4; ++n_) {                               \
                acc[m_][n_] = __builtin_amdgcn_mfma_f32_16x16x32_bf16(a_[0][m_], b_[0][n_], acc[m_][n_], 0, 0, 0); \
                acc[m_][n_] = __builtin_amdgcn_mfma_f32_16x16x32_bf16(a_[1][m_], b_[1][n_], acc[m_][n_], 0, 0, 0); \
            }                                                              \
    }

// 4(m) x 2(n) frag compute, wave rows wm*64, cols wn*32 (128x64 tile) — qkv.
#define COMPUTE_Q2(AS, BS)                                                 \
    {                                                                      \
        bf16x8_t a_[2][4], b_[2][2];                                       \
        _Pragma("unroll")                                                  \
        for (int ks_ = 0; ks_ < 2; ++ks_) {                                \
            _Pragma("unroll")                                              \
            for (int m_ = 0; m_ < 4; ++m_) {                               \
                const int ra_ = wm*64 + m_*16 + l15;                       \
                a_[ks_][m_] = *(const bf16x8_t*)&(AS)[ra_*64 + ((ks_*4 + lhi) ^ (ra_ & 7))*8]; \
            }                                                              \
            _Pragma("unroll")                                              \
            for (int n_ = 0; n_ < 2; ++n_) {                               \
                const int rb_ = wn*32 + n_*16 + l15;                       \
                b_[ks_][n_] = *(const bf16x8_t*)&(BS)[rb_*64 + ((ks_*4 + lhi) ^ (rb_ & 7))*8]; \
            }                                                              \
        }                                                                  \
        _Pragma("unroll")                                                  \
        for (int m_ = 0; m_ < 4; ++m_)                                     \
            _Pragma("unroll")                                              \
            for (int n_ = 0; n_ < 2; ++n_) {                               \
                acc[m_][n_] = __builtin_amdgcn_mfma_f32_16x16x32_bf16(a_[0][m_], b_[0][n_], acc[m_][n_], 0, 0, 0); \
                acc[m_][n_] = __builtin_amdgcn_mfma_f32_16x16x32_bf16(a_[1][m_], b_[1][n_], acc[m_][n_], 0, 0, 0); \
            }                                                              \
    }

// ---------------- pre-pass: x f32 -> bf16 (same layout)
__global__ __launch_bounds__(256) void convert_x(
    const float* __restrict__ src, unsigned short* __restrict__ dst)
{
    const int i = blockIdx.x * 256 + threadIdx.x;
    const float4 v = ((const float4*)src)[i];
    ushort4 o; o.x = f2bf(v.x); o.y = f2bf(v.y); o.z = f2bf(v.z); o.w = f2bf(v.w);
    ((ushort4*)dst)[i] = o;
}

// ---------------- pre-pass: W [R][C] f32 -> Wt [C][R] bf16
__global__ __launch_bounds__(256) void transpose_cvt(
    const float* __restrict__ src, unsigned short* __restrict__ dst, int R, int C)
{
    __shared__ unsigned short tile[32][33];
    const int tx = threadIdx.x & 31, ty = threadIdx.x >> 5;
    const int bx = blockIdx.x, by = blockIdx.y;
    #pragma unroll
    for (int j = 0; j < 32; j += 8)
        tile[ty + j][tx] = f2bf(src[(size_t)(by*32 + ty + j) * C + bx*32 + tx]);
    __syncthreads();
    #pragma unroll
    for (int j = 0; j < 32; j += 8)
        dst[(size_t)(bx*32 + ty + j) * R + by*32 + tx] = tile[tx][ty + j];
}

// ---------------- GEMM1: 128x64 tile, 4 waves, 24KB, packed vT stores
__global__ __launch_bounds__(256, 6) void gemm_qkv_bf16(
    const unsigned short* __restrict__ A, const unsigned short* __restrict__ Bt,
    const float* __restrict__ bias,
    unsigned short* __restrict__ q, unsigned short* __restrict__ kO,
    unsigned short* __restrict__ vT)
{
    __shared__ unsigned short As[128*64];   // 16KB
    __shared__ unsigned short Bs[64*64];    // 8KB
    const int tid = threadIdx.x;
    const int id = blockIdx.x;              // 2304 blocks, 2304%8==0
    const int xcd = id & 7, r = id >> 3;    // r 0..287
    const int nb = r >> 3;                  // 0..35 (one 96KB panel per 8 blocks)
    const int mb = (r & 7) * 8 + xcd;       // 0..63 (8 per XCD, pinned)
    const int n0 = nb * 64, m0 = mb * 128;

    const int lane = tid & 63, w = tid >> 6;
    const int l15 = lane & 15, lhi = lane >> 4;
    const int wm = w >> 1, wn = w & 1;      // 2x2 wave grid
    const int wb = tid & 192;

    const unsigned short* Ab = A  + (size_t)m0 * 768;
    const unsigned short* Bb = Bt + (size_t)n0 * 768;

    f32x4_t acc[4][2] = {};

    #pragma unroll 1
    for (int t = 0; t < 12; ++t) {
        STAGE_TILE(As, Ab, t*64, 4, 256)
        STAGE_TILE(Bs, Bb, t*64, 2, 256)
        WAIT0; BAR;
        COMPUTE_Q2(As, Bs)
        BAR;
    }

    // epilogue: qkv scatter. kk block-uniform (64 | 768).
    // q pre-scaled by D^-0.5 * log2(e) so attn can use exp2 directly.
    #pragma unroll
    for (int n = 0; n < 2; ++n) {
        const int gcol = n0 + wn*32 + n*16 + l15;         // 0..2303
        const int kk = gcol / 768;                        // 0=q,1=k,2=v
        const int rr = gcol - kk*768;
        const int h  = rr >> 6, d = rr & 63;
        const float bv = bias[gcol];
        const float sc = (kk == 0) ? 0.18033688f : 1.0f;  // 0.125 * log2(e)
        #pragma unroll
        for (int m = 0; m < 4; ++m) {
            const int grow_base = m0 + wm*64 + m*16 + lhi*4;  // 4-aligned, one b
            const int bb = grow_base >> 10, seq0 = grow_base & 1023;
            const size_t bh = (size_t)bb*12 + h;
            ushort4 o4;
            o4.x = f2bf((acc[m][n][0] + bv) * sc);
            o4.y = f2bf((acc[m][n][1] + bv) * sc);
            o4.z = f2bf((acc[m][n][2] + bv) * sc);
            o4.w = f2bf((acc[m][n][3] + bv) * sc);
            if (kk == 2) {                    // v: 4 consecutive seq -> one 8B store
                *(ushort4*)(vT + (bh*64 + d)*1024 + seq0) = o4;
            } else {
                unsigned short* dst = (kk == 0) ? q : kO;
                dst[(bh*1024 + seq0 + 0)*64 + d] = o4.x;
                dst[(bh*1024 + seq0 + 1)*64 + d] = o4.y;
                dst[(bh*1024 + seq0 + 2)*64 + d] = o4.z;
                dst[(bh*1024 + seq0 + 3)*64 + d] = o4.w;
            }
        }
    }
}

// ---------------- Attention: K+V+P in LDS, exp2 softmax, truncated P
__global__ __launch_bounds__(512, 6) void attn2(
    const unsigned short* __restrict__ q, const unsigned short* __restrict__ k,
    const unsigned short* __restrict__ vT, unsigned short* __restrict__ obuf)
{
    __shared__ unsigned short Ks[64 * 72];
    __shared__ unsigned short Vs[64 * 72];
    __shared__ unsigned short P[8][16 * 72];   // stride 72: b128 reads 16B-aligned
    const int tid = threadIdx.x;
    const int id = blockIdx.x;                 // 768 blocks, 768%8==0
    const int swz = (id & 7) * 96 + (id >> 3);
    const int qt = swz & 7, bh = swz >> 3;     // 8 q-tiles of 128, 96 bh

    const int lane = tid & 63, w = tid >> 6;   // w 0..7
    const int l15 = lane & 15, lhi = lane >> 4;
    const unsigned short* qp = q  + (size_t)bh * 65536;
    const unsigned short* kp = k  + (size_t)bh * 65536;
    const unsigned short* vp = vT + (size_t)bh * 65536;  // [64 d][1024 n]

    bf16x8_t qf[2];
    const int qrow = qt*128 + w*16 + l15;
    #pragma unroll
    for (int ks = 0; ks < 2; ++ks)
        qf[ks] = *(const bf16x8_t*)(qp + (size_t)qrow*64 + ks*32 + lhi*8);

    f32x4_t acco[4] = {};
    float lsum[4] = {0.f, 0.f, 0.f, 0.f};
    unsigned short* Pw = P[w];

    const int r8 = tid >> 3, cb = (tid & 7) * 8;
    bf16x8_t kr, vr;
    kr = *(const bf16x8_t*)(kp + (size_t)r8*64 + cb);
    vr = *(const bf16x8_t*)(vp + (size_t)r8*1024 + cb);
    *(bf16x8_t*)&Ks[r8*72 + cb] = kr;
    *(bf16x8_t*)&Vs[r8*72 + cb] = vr;

    for (int kt = 0; kt < 16; ++kt) {
        __syncthreads();
        if (kt < 15) {                         // T14: issue next-tile loads now
            kr = *(const bf16x8_t*)(kp + (size_t)((kt+1)*64 + r8)*64 + cb);
            vr = *(const bf16x8_t*)(vp + (size_t)r8*1024 + (kt+1)*64 + cb);
        }

        f32x4_t accs[4] = {};
        __builtin_amdgcn_s_setprio(1);
        #pragma unroll
        for (int c = 0; c < 4; ++c)
            #pragma unroll
            for (int ks = 0; ks < 2; ++ks) {
                bf16x8_t kf = *(const bf16x8_t*)&Ks[(c*16 + l15)*72 + ks*32 + lhi*8];
                accs[c] = __builtin_amdgcn_mfma_f32_16x16x32_bf16(qf[ks], kf, accs[c], 0, 0, 0);
            }
        __builtin_amdgcn_s_setprio(0);

        // softmax numerator: S pre-scaled by log2(e) -> exp2; truncated bf16.
        #pragma unroll
        for (int c = 0; c < 4; ++c)
            #pragma unroll
            for (int r = 0; r < 4; ++r) {
                const float pv = __builtin_amdgcn_exp2f(accs[c][r]);
                lsum[r] += pv;
                union { float f; unsigned u; } uu; uu.f = pv;
                Pw[(lhi*4 + r)*72 + c*16 + l15] = (unsigned short)(uu.u >> 16);
            }

        bf16x8_t pf[2];
        #pragma unroll
        for (int ks = 0; ks < 2; ++ks)
            pf[ks] = *(const bf16x8_t*)&Pw[l15*72 + ks*32 + lhi*8];
        __builtin_amdgcn_s_setprio(1);
        #pragma unroll
        for (int n = 0; n < 4; ++n)
            #pragma unroll
            for (int ks = 0; ks < 2; ++ks) {
                bf16x8_t vf = *(const bf16x8_t*)&Vs[(n*16 + l15)*72 + ks*32 + lhi*8];
                acco[n] = __builtin_amdgcn_mfma_f32_16x16x32_bf16(pf[ks], vf, acco[n], 0, 0, 0);
            }
        __builtin_amdgcn_s_setprio(0);

        __syncthreads();
        if (kt < 15) {                         // write-late into single buffer
            *(bf16x8_t*)&Ks[r8*72 + cb] = kr;
            *(bf16x8_t*)&Vs[r8*72 + cb] = vr;
        }
    }

    #pragma unroll
    for (int r = 0; r < 4; ++r)
        #pragma unroll
        for (int off = 1; off <= 8; off <<= 1)
            lsum[r] += __shfl_xor(lsum[r], off, 64);

    const int b = bh / 12, h = bh % 12;
    #pragma unroll
    for (int n = 0; n < 4; ++n)
        #pragma unroll
        for (int r = 0; r < 4; ++r) {
            const int seq = qt*128 + w*16 + lhi*4 + r;
            obuf[((size_t)(b*1024 + seq))*768 + h*64 + n*16 + l15] = f2bf(acco[n][r] / lsum[r]);
        }
}

// ---------------- GEMM2: 64x128 tile, 4 waves, 24KB buffer
__global__ __launch_bounds__(256, 6) void gemm_proj_bf16(
    const unsigned short* __restrict__ A, const unsigned short* __restrict__ Bt,
    const float* __restrict__ bias, float* __restrict__ out)
{
    __shared__ unsigned short As[64*64];
    __shared__ unsigned short Bs[128*64];
    const int tid = threadIdx.x;
    const int id = blockIdx.x;              // 768 blocks
    const int swz = (id & 7) * 96 + (id >> 3);
    const int n0 = (swz % 6) * 128, m0 = (swz / 6) * 64;

    const int lane = tid & 63, w = tid >> 6;
    const int l15 = lane & 15, lhi = lane >> 4;
    const int wm = w >> 1, wn = w & 1;
    const int wb = tid & 192;

    const unsigned short* Ab = A  + (size_t)m0 * 768;
    const unsigned short* Bb = Bt + (size_t)n0 * 768;

    f32x4_t acc[2][4] = {};

    #pragma unroll 1
    for (int t = 0; t < 12; ++t) {
        STAGE_TILE(As, Ab, t*64, 2, 256)
        STAGE_TILE(Bs, Bb, t*64, 4, 256)
        WAIT0; BAR;
        COMPUTE_P(As, Bs)
        BAR;
    }

    #pragma unroll
    for (int n = 0; n < 4; ++n) {
        const int gcol = n0 + wn*64 + n*16 + l15;
        const float bv = bias[gcol];
        #pragma unroll
        for (int m = 0; m < 2; ++m) {
            const int grow_base = m0 + wm*32 + m*16 + lhi*4;
            #pragma unroll
            for (int reg = 0; reg < 4; ++reg)
                out[(size_t)(grow_base + reg)*768 + gcol] = acc[m][n][reg] + bv;
        }
    }
}

extern "C" void kernel_launch(void* const* d_in, const int* in_sizes, int n_in,
                              void* d_out, int out_size, void* d_ws, size_t ws_size,
                              hipStream_t stream) {
    const float* x     = (const float*)d_in[0];
    const float* Wqkv  = (const float*)d_in[1];
    const float* bqkv  = (const float*)d_in[2];
    const float* Wproj = (const float*)d_in[3];
    const float* bproj = (const float*)d_in[4];
    float* out = (float*)d_out;
    unsigned short* ws = (unsigned short*)d_ws;

    unsigned short* xb    = ws;                       // 6291456
    unsigned short* obuf  = ws;                       // alias (xb dead after gemm_qkv)
    unsigned short* wqt   = ws + 6291456u;            // 1769472
    unsigned short* wpt   = ws + 8060928u;            // 589824
    unsigned short* qb    = ws + 8650752u;            // 6291456
    unsigned short* kb    = ws + 14942208u;           // 6291456
    unsigned short* vTb   = ws + 21233664u;           // 6291456

    convert_x     <<<6144, 256, 0, stream>>>(x, xb);
    transpose_cvt <<<dim3(72, 24), 256, 0, stream>>>(Wqkv, wqt, 768, 2304);
    transpose_cvt <<<dim3(24, 24), 256, 0, stream>>>(Wproj, wpt, 768, 768);
    gemm_qkv_bf16 <<<2304, 256, 0, stream>>>(xb, wqt, bqkv, qb, kb, vTb);
    attn2         <<<768,  512, 0, stream>>>(qb, kb, vTb, obuf);
    gemm_proj_bf16<<<768,  256, 0, stream>>>(obuf, wpt, bproj, out);
}